// Round 4
// baseline (208.067 us; speedup 1.0000x reference)
//
#include <hip/hip_runtime.h>

// Multi-step LIF forward (T=4, tau=2, hard reset to 0, v_th=1).
// Forward value of the STE spike is just heaviside(v_charged - 1).
// Each thread owns 4 consecutive (b,n) lanes (one 16B vector), carries the
// membrane potential in registers across the T=4 sequential steps.
// Pure streaming: 512 MiB in + 512 MiB out, memory-bound.
// R4: NT hints removed (A/B vs round 2's NT version) — plain cache path.

#define T_STEPS 4

typedef float f4 __attribute__((ext_vector_type(4)));

__global__ __launch_bounds__(256) void lif_fwd_kernel(
    const f4* __restrict__ x, f4* __restrict__ out, int bn4) {
    const int stride = gridDim.x * blockDim.x;
    for (int i = blockIdx.x * blockDim.x + threadIdx.x; i < bn4; i += stride) {
        f4 v = {0.0f, 0.0f, 0.0f, 0.0f};
#pragma unroll
        for (int t = 0; t < T_STEPS; ++t) {
            const size_t off = (size_t)t * (size_t)bn4 + (size_t)i;
            f4 xv = x[off];
            f4 s;
#pragma unroll
            for (int j = 0; j < 4; ++j) {
                // v_charged = v + (x - v) * 0.5   (matches ref v + (x - v)/tau)
                float vc = v[j] + (xv[j] - v[j]) * 0.5f;
                bool fire = (vc >= 1.0f);
                s[j] = fire ? 1.0f : 0.0f;
                v[j] = fire ? 0.0f : vc;   // hard reset to V_RESET = 0
            }
            out[off] = s;
        }
    }
}

extern "C" void kernel_launch(void* const* d_in, const int* in_sizes, int n_in,
                              void* d_out, int out_size, void* d_ws, size_t ws_size,
                              hipStream_t stream) {
    const float* x = (const float*)d_in[0];
    float* out = (float*)d_out;

    const long long total = (long long)in_sizes[0];   // T*B*N = 134,217,728
    const long long bn = total / T_STEPS;             // B*N = 33,554,432
    const int bn4 = (int)(bn / 4);                    // 16B columns = 8,388,608

    const int block = 256;
    long long want = (bn4 + block - 1) / block;
    int grid = (int)(want < 2048 ? want : 2048);      // grid-stride the rest

    lif_fwd_kernel<<<grid, block, 0, stream>>>(
        (const f4*)x, (f4*)out, bn4);
}

// Round 5
// 181.509 us; speedup vs baseline: 1.1463x; 1.1463x over previous
//
#include <hip/hip_runtime.h>

// Multi-step LIF forward (T=4, tau=2, hard reset to 0, v_th=1).
// Forward value of the STE spike is just heaviside(v_charged - 1).
// Each thread owns exactly ONE 16B column (4 consecutive (b,n) lanes),
// carries v in registers across the T=4 sequential steps, then retires —
// exact-sized grid, no grid-stride loop, letting fresh waves overlap
// retiring waves' store drains.
// NT hints kept: measured +6% (R2 vs R4) — touch-once streams bypass LLC.
// Pure streaming: 512 MiB in + 512 MiB out, memory-bound.

#define T_STEPS 4

typedef float f4 __attribute__((ext_vector_type(4)));

__global__ __launch_bounds__(256) void lif_fwd_kernel(
    const f4* __restrict__ x, f4* __restrict__ out, int bn4) {
    const int i = blockIdx.x * blockDim.x + threadIdx.x;
    if (i >= bn4) return;
    f4 v = {0.0f, 0.0f, 0.0f, 0.0f};
#pragma unroll
    for (int t = 0; t < T_STEPS; ++t) {
        const size_t off = (size_t)t * (size_t)bn4 + (size_t)i;
        f4 xv = __builtin_nontemporal_load(&x[off]);
        f4 s;
#pragma unroll
        for (int j = 0; j < 4; ++j) {
            // v_charged = v + (x - v) * 0.5   (matches ref v + (x - v)/tau)
            float vc = v[j] + (xv[j] - v[j]) * 0.5f;
            bool fire = (vc >= 1.0f);
            s[j] = fire ? 1.0f : 0.0f;
            v[j] = fire ? 0.0f : vc;   // hard reset to V_RESET = 0
        }
        __builtin_nontemporal_store(s, &out[off]);
    }
}

extern "C" void kernel_launch(void* const* d_in, const int* in_sizes, int n_in,
                              void* d_out, int out_size, void* d_ws, size_t ws_size,
                              hipStream_t stream) {
    const float* x = (const float*)d_in[0];
    float* out = (float*)d_out;

    const long long total = (long long)in_sizes[0];   // T*B*N = 134,217,728
    const long long bn = total / T_STEPS;             // B*N = 33,554,432
    const int bn4 = (int)(bn / 4);                    // 16B columns = 8,388,608

    const int block = 256;
    const int grid = (int)((bn4 + block - 1) / block); // 32768 blocks, exact

    lif_fwd_kernel<<<grid, block, 0, stream>>>(
        (const f4*)x, (f4*)out, bn4);
}